// Round 14
// baseline (1863.323 us; speedup 1.0000x reference)
//
#include <hip/hip_runtime.h>
#include <cstdint>
#include <cstddef>

#define VSZ 32000
#define ED  512
#define HD  512
#define SQ  128
#define BA  64
#define INW 1024
#define NG  1536
#define NWG 32
#define NGW 448   // gemm-consumer WGs in the fused kernel
#define FLG 32    // flag stride in dwords (one 128B line per wave-slot)

typedef __attribute__((ext_vector_type(8))) short sh8;
typedef __attribute__((ext_vector_type(4))) float f32x4;
typedef _Float16 half8 __attribute__((ext_vector_type(8)));
typedef unsigned u32x4 __attribute__((ext_vector_type(4)));

typedef __attribute__((address_space(1))) const void glob_cv;
typedef __attribute__((address_space(3))) void lds_v;

__device__ inline unsigned short f2bf(float f) {
  unsigned int u = __float_as_uint(f);
  u += 0x7fffu + ((u >> 16) & 1u);
  return (unsigned short)(u >> 16);
}

// Device-scope (bypass L1+L2, L3 coherence point) accessors. Burst-issue loads,
// then ONE s_waitcnt vmcnt(0) + sched_barrier(0) before consuming (rule #18).
__device__ __forceinline__ half8 ld_h8_dev(const _Float16* p) {
  u32x4 r;
  asm volatile("global_load_dwordx4 %0, %1, off sc0 sc1" : "=v"(r) : "v"(p));
  return __builtin_bit_cast(half8, r);
}

__device__ __forceinline__ u32x4 ld_q_dev(const unsigned short* p) {
  u32x4 r;
  asm volatile("global_load_dwordx4 %0, %1, off sc0 sc1" : "=v"(r) : "v"(p));
  return r;
}

__device__ __forceinline__ void st_u32_dev(unsigned* p, unsigned v) {
  asm volatile("global_store_dword %0, %1, off sc0 sc1" :: "v"(p), "v"(v) : "memory");
}

__device__ __forceinline__ unsigned ld_u32_dev(const unsigned* p) {
  unsigned r;
  asm volatile("global_load_dword %0, %1, off sc0 sc1" : "=v"(r) : "v"(p));
  asm volatile("s_waitcnt vmcnt(0)" ::: "memory");
  __builtin_amdgcn_sched_barrier(0);
  return r;
}

// Wave-autonomous signal: drain this wave's device-scope data stores, then publish.
__device__ __forceinline__ void wave_signal(unsigned* flags, unsigned epoch, int slot, int lane) {
  asm volatile("s_waitcnt vmcnt(0)" ::: "memory");
  if (lane == 0) st_u32_dev(flags + slot * FLG, epoch);
  __builtin_amdgcn_sched_barrier(0);
}

// Wave-autonomous wait: lane l polls producer-WG (l&31)'s wave-wv flag.
__device__ __forceinline__ void wave_wait(const unsigned* flags, unsigned epoch, int wv, int lane) {
  const unsigned* fp = flags + (((lane & 31) << 2) + wv) * FLG;
  unsigned v = ld_u32_dev(fp);
  while (!__all((int)(v >= epoch))) v = ld_u32_dev(fp);
}

// ---------------- pre-projection (fp16 MFMA): XG = emb[x] @ {Wr,Wz,Wh}[:,:512]^T + bias ------
__global__ __launch_bounds__(256) void proj_kernel(
    const int* __restrict__ x, const float* __restrict__ emb,
    const float* __restrict__ Wr, const float* __restrict__ Br,
    const float* __restrict__ Wz, const float* __restrict__ Bz,
    const float* __restrict__ Wh, const float* __restrict__ Bh,
    float* __restrict__ XG)
{
  __shared__ _Float16 As[128 * 40];
  __shared__ _Float16 Bs[128 * 40];
  const int tn = blockIdx.x;           // 0..11 (N tile; gate = tn>>2, no straddle)
  const int tm = blockIdx.y;           // 0..63 (M tile)
  const int g  = tn >> 2;
  const float* Wsrc = (g == 0 ? Wr : (g == 1 ? Wz : Wh));
  const float* Bias = (g == 0 ? Br : (g == 1 ? Bz : Bh));
  const int jj0 = (tn & 3) * 128;
  const int tid = threadIdx.x;
  const int wave = tid >> 6, lane = tid & 63;
  const int wm = wave >> 1, wn = wave & 1;
  const int l15 = lane & 15, lhi = lane >> 4;
  f32x4 acc[4][4] = {};

  for (int k0 = 0; k0 < ED; k0 += 32) {
    #pragma unroll
    for (int it = 0; it < 2; ++it) {
      const int c = tid + it * 256;
      const int row = c >> 2, c8 = (c & 3) << 3;
      {
        const int src = x[tm * 128 + row];
        const float4 a0 = *(const float4*)(emb + (size_t)src * ED + k0 + c8);
        const float4 a1 = *(const float4*)(emb + (size_t)src * ED + k0 + c8 + 4);
        half8 w;
        w[0]=(_Float16)a0.x; w[1]=(_Float16)a0.y; w[2]=(_Float16)a0.z; w[3]=(_Float16)a0.w;
        w[4]=(_Float16)a1.x; w[5]=(_Float16)a1.y; w[6]=(_Float16)a1.z; w[7]=(_Float16)a1.w;
        *(half8*)(As + row * 40 + c8) = w;
      }
      {
        const float* wr = Wsrc + (size_t)(jj0 + row) * INW + k0 + c8;
        const float4 b0 = *(const float4*)(wr);
        const float4 b1 = *(const float4*)(wr + 4);
        half8 w;
        w[0]=(_Float16)b0.x; w[1]=(_Float16)b0.y; w[2]=(_Float16)b0.z; w[3]=(_Float16)b0.w;
        w[4]=(_Float16)b1.x; w[5]=(_Float16)b1.y; w[6]=(_Float16)b1.z; w[7]=(_Float16)b1.w;
        *(half8*)(Bs + row * 40 + c8) = w;
      }
    }
    __syncthreads();
    half8 af[4], bf[4];
    #pragma unroll
    for (int mi = 0; mi < 4; ++mi)
      af[mi] = *(const half8*)(As + (wm * 64 + mi * 16 + l15) * 40 + lhi * 8);
    #pragma unroll
    for (int ni = 0; ni < 4; ++ni)
      bf[ni] = *(const half8*)(Bs + (wn * 64 + ni * 16 + l15) * 40 + lhi * 8);
    #pragma unroll
    for (int mi = 0; mi < 4; ++mi)
      #pragma unroll
      for (int ni = 0; ni < 4; ++ni)
        acc[mi][ni] = __builtin_amdgcn_mfma_f32_16x16x32_f16(af[mi], bf[ni], acc[mi][ni], 0, 0, 0);
    __syncthreads();
  }
  #pragma unroll
  for (int ni = 0; ni < 4; ++ni) {
    const int jc = tn * 128 + wn * 64 + ni * 16 + l15;
    const float bv = Bias[jj0 + wn * 64 + ni * 16 + l15];
    #pragma unroll
    for (int mi = 0; mi < 4; ++mi) {
      const int m0 = tm * 128 + wm * 64 + mi * 16 + lhi * 4;
      #pragma unroll
      for (int q = 0; q < 4; ++q)
        XG[(size_t)(m0 + q) * NG + jc] = acc[mi][ni][q] + bv;
    }
  }
}

// ---------------- W f32 -> bf16 one-shot conversion ------------------------------------------
__global__ __launch_bounds__(256) void wconv_kernel(const float* __restrict__ W,
                                                    unsigned short* __restrict__ Wbf)
{
  const size_t i = ((size_t)blockIdx.x * 256 + threadIdx.x) * 8;
  const float4 a = *(const float4*)(W + i);
  const float4 b = *(const float4*)(W + i + 4);
  union { unsigned short h[8]; uint4 u; } cv;
  cv.h[0] = f2bf(a.x); cv.h[1] = f2bf(a.y); cv.h[2] = f2bf(a.z); cv.h[3] = f2bf(a.w);
  cv.h[4] = f2bf(b.x); cv.h[5] = f2bf(b.y); cv.h[6] = f2bf(b.z); cv.h[7] = f2bf(b.w);
  *(uint4*)(Wbf + i) = cv.u;
}

// ---------------- FUSED: recurrence producers (WG 0..31) + flag-gated GEMM consumers ---------
// Producers: r11 wave-autonomous recurrence; Habf stores device-scope and BEFORE flagsB signal.
// Consumers: 128x128 bf16 tiles of Y = Habf @ Wbf^T + b; tile tm waits for epoch >= 2tm+2 on
// all 128 flagsB slots. Tiles ordered tm=4..63 then 0..3 (XG overlays Y rows < 394).
__global__ __launch_bounds__(256) void fused_kernel(
    const float* __restrict__ XG,
    const float* __restrict__ Wr, const float* __restrict__ Wz, const float* __restrict__ Wh,
    _Float16* __restrict__ hF, _Float16* __restrict__ uF,
    unsigned short* __restrict__ Habf,
    float* __restrict__ outT,
    unsigned* __restrict__ flagsA, unsigned* __restrict__ flagsB,
    const unsigned short* __restrict__ Wbf,
    const float* __restrict__ bias,
    float* __restrict__ Y)
{
  __shared__ unsigned short As[128 * 32];
  __shared__ unsigned short Bs[128 * 32];
  const int tid = threadIdx.x, wg = blockIdx.x;
  const int wv = tid >> 6, lane = tid & 63;
  const int l15 = lane & 15, lhi = lane >> 4;

  if (wg < NWG) {
    // ================= producer: GRU recurrence =================
    const int mrow = wv * 16 + l15;
    const int col  = wg * 16 + l15;
    const int slot = wg * 4 + wv;

    half8 wfR[16], wfZ[16], wfH[16];
    {
      const float* WR = Wr + (size_t)col * INW + ED + lhi * 8;
      const float* WZ = Wz + (size_t)col * INW + ED + lhi * 8;
      const float* WH = Wh + (size_t)col * INW + ED + lhi * 8;
      #pragma unroll
      for (int s = 0; s < 16; ++s) {
        float4 a, b; half8 w;
        a = *(const float4*)(WR + s * 32); b = *(const float4*)(WR + s * 32 + 4);
        w[0]=(_Float16)a.x; w[1]=(_Float16)a.y; w[2]=(_Float16)a.z; w[3]=(_Float16)a.w;
        w[4]=(_Float16)b.x; w[5]=(_Float16)b.y; w[6]=(_Float16)b.z; w[7]=(_Float16)b.w;
        wfR[s] = w;
        a = *(const float4*)(WZ + s * 32); b = *(const float4*)(WZ + s * 32 + 4);
        w[0]=(_Float16)a.x; w[1]=(_Float16)a.y; w[2]=(_Float16)a.z; w[3]=(_Float16)a.w;
        w[4]=(_Float16)b.x; w[5]=(_Float16)b.y; w[6]=(_Float16)b.z; w[7]=(_Float16)b.w;
        wfZ[s] = w;
        a = *(const float4*)(WH + s * 32); b = *(const float4*)(WH + s * 32 + 4);
        w[0]=(_Float16)a.x; w[1]=(_Float16)a.y; w[2]=(_Float16)a.z; w[3]=(_Float16)a.w;
        w[4]=(_Float16)b.x; w[5]=(_Float16)b.y; w[6]=(_Float16)b.z; w[7]=(_Float16)b.w;
        wfH[s] = w;
      }
    }

    float hreg[4] = {0.f, 0.f, 0.f, 0.f};
    float zreg[4];
    float xgR[4], xgZ[4], xgH[4];
    #pragma unroll
    for (int q = 0; q < 4; ++q) {
      const int b = wv * 16 + lhi * 4 + q;
      const float* xp = XG + (size_t)b * NG + col;
      xgR[q] = xp[0]; xgZ[q] = xp[512]; xgH[q] = xp[1024];
    }

    for (int t = 0; t < SQ; ++t) {
      const unsigned ep = (unsigned)(t + 1);
      wave_wait(flagsB, (unsigned)t, wv, lane);

      half8 ha[16];
      #pragma unroll
      for (int s = 0; s < 16; ++s)
        ha[s] = ld_h8_dev(hF + (size_t)mrow * HD + s * 32 + lhi * 8);
      asm volatile("s_waitcnt vmcnt(0)" ::: "memory");
      __builtin_amdgcn_sched_barrier(0);

      f32x4 accR = {};
      #pragma unroll
      for (int s = 0; s < 16; ++s)
        accR = __builtin_amdgcn_mfma_f32_16x16x32_f16(ha[s], wfR[s], accR, 0, 0, 0);
      #pragma unroll
      for (int q = 0; q < 4; ++q) {
        const int b = wv * 16 + lhi * 4 + q;
        const float r = 1.0f / (1.0f + __expf(-(accR[q] + xgR[q])));
        const _Float16 uh = (_Float16)(r * hreg[q]);
        const unsigned short ub = __builtin_bit_cast(unsigned short, uh);
        const unsigned short ob = (unsigned short)__shfl_xor((int)ub, 1);
        if (!(l15 & 1))
          st_u32_dev((unsigned*)(uF + (size_t)b * HD + col),
                     (unsigned)ub | ((unsigned)ob << 16));
      }
      wave_signal(flagsA, ep, slot, lane);

      f32x4 accZ = {};
      #pragma unroll
      for (int s = 0; s < 16; ++s)
        accZ = __builtin_amdgcn_mfma_f32_16x16x32_f16(ha[s], wfZ[s], accZ, 0, 0, 0);
      float nR[4] = {0,0,0,0}, nZ[4] = {0,0,0,0}, nH[4] = {0,0,0,0};
      if (t + 1 < SQ) {
        #pragma unroll
        for (int q = 0; q < 4; ++q) {
          const int b = wv * 16 + lhi * 4 + q;
          const float* xp = XG + (size_t)(t + 1) * BA * NG + (size_t)b * NG + col;
          nR[q] = xp[0]; nZ[q] = xp[512]; nH[q] = xp[1024];
        }
      }
      #pragma unroll
      for (int q = 0; q < 4; ++q)
        zreg[q] = 1.0f / (1.0f + __expf(-(accZ[q] + xgZ[q])));

      wave_wait(flagsA, ep, wv, lane);
      half8 ua[16];
      #pragma unroll
      for (int s = 0; s < 16; ++s)
        ua[s] = ld_h8_dev(uF + (size_t)mrow * HD + s * 32 + lhi * 8);
      asm volatile("s_waitcnt vmcnt(0)" ::: "memory");
      __builtin_amdgcn_sched_barrier(0);
      f32x4 acc = {};
      #pragma unroll
      for (int s = 0; s < 16; ++s)
        acc = __builtin_amdgcn_mfma_f32_16x16x32_f16(ua[s], wfH[s], acc, 0, 0, 0);

      #pragma unroll
      for (int q = 0; q < 4; ++q) {
        const int b = wv * 16 + lhi * 4 + q;
        const float e  = __expf(2.0f * (acc[q] + xgH[q]));   // tanh, inf-safe
        const float hc = 1.0f - 2.0f / (e + 1.0f);
        const float hn = zreg[q] * hreg[q] + (1.0f - zreg[q]) * hc;
        hreg[q] = hn;
        const _Float16 hh = (_Float16)hn;
        const unsigned short hb = __builtin_bit_cast(unsigned short, hh);
        const unsigned short hob = (unsigned short)__shfl_xor((int)hb, 1);
        const unsigned short bb = f2bf(hn);
        const unsigned short bob = (unsigned short)__shfl_xor((int)bb, 1);
        if (!(l15 & 1)) {
          st_u32_dev((unsigned*)(hF + (size_t)b * HD + col),
                     (unsigned)hb | ((unsigned)hob << 16));
          // history store BEFORE the signal: flag visibility implies row-t at L3
          st_u32_dev((unsigned*)(Habf + (size_t)(t * BA + b) * HD + col),
                     (unsigned)bb | ((unsigned)bob << 16));
        }
      }
      wave_signal(flagsB, ep, slot, lane);

      #pragma unroll
      for (int q = 0; q < 4; ++q) {
        const int b = wv * 16 + lhi * 4 + q;
        if (t == SQ - 1) outT[col * BA + b] = hreg[q];
        xgR[q] = nR[q]; xgZ[q] = nZ[q]; xgH[q] = nH[q];
      }
    }
  } else {
    // ================= consumer: flag-gated output GEMM =================
    const int wgg = wg - NWG;                 // 0..447
    const int wave = wv;
    const int wm = wave >> 1, wn = wave & 1;
    const int srow = wave * 16 + (lane >> 2); // B-staging source row (+ i*64)
    const int scol = (lane & 3) * 8;

    for (int tau = wgg; tau < 16000; tau += NGW) {
      const int rd = tau / 250;
      const int tn = tau - rd * 250;
      const int tm = (rd + 4) & 63;           // tm 4..63 first, 0..3 last (XG alias)
      const unsigned need = (unsigned)(2 * tm + 2);
      {
        const unsigned* f0 = flagsB + lane * FLG;          // slots 0..63
        const unsigned* f1 = flagsB + (64 + lane) * FLG;   // slots 64..127
        unsigned va = ld_u32_dev(f0), vb = ld_u32_dev(f1);
        while (!__all((int)((va >= need) & (vb >= need)))) {
          va = ld_u32_dev(f0); vb = ld_u32_dev(f1);
        }
      }

      f32x4 acc[4][4] = {};
      for (int k0 = 0; k0 < 512; k0 += 32) {
        // B: async global->LDS (Wbf from a prior dispatch; boundary-coherent)
        #pragma unroll
        for (int i = 0; i < 2; ++i) {
          const unsigned short* gB =
              Wbf + (size_t)(tn * 128 + i * 64 + srow) * 512 + k0 + scol;
          __builtin_amdgcn_global_load_lds((glob_cv*)gB,
              (lds_v*)(Bs + i * 2048 + wave * 512), 16, 0, 0);
        }
        // A: reg-staged device-scope loads (Habf freshly written by producers)
        u32x4 ra[2];
        #pragma unroll
        for (int it = 0; it < 2; ++it) {
          const int ss = tid + it * 256;
          const int row = ss >> 2, c8 = (ss & 3) << 3;
          ra[it] = ld_q_dev(Habf + (size_t)(tm * 128 + row) * 512 + k0 + c8);
        }
        asm volatile("s_waitcnt vmcnt(0)" ::: "memory");
        __builtin_amdgcn_sched_barrier(0);
        #pragma unroll
        for (int it = 0; it < 2; ++it) {
          const int ss = tid + it * 256;
          const int row = ss >> 2, c8 = (ss & 3) << 3;
          *(u32x4*)(As + row * 32 + c8) = ra[it];
        }
        __syncthreads();
        sh8 af[4], bfr[4];
        #pragma unroll
        for (int mi = 0; mi < 4; ++mi)
          af[mi] = *(const sh8*)(As + (wm * 64 + mi * 16 + l15) * 32 + lhi * 8);
        #pragma unroll
        for (int ni = 0; ni < 4; ++ni)
          bfr[ni] = *(const sh8*)(Bs + (wn * 64 + ni * 16 + l15) * 32 + lhi * 8);
        #pragma unroll
        for (int mi = 0; mi < 4; ++mi)
          #pragma unroll
          for (int ni = 0; ni < 4; ++ni)
            acc[mi][ni] = __builtin_amdgcn_mfma_f32_16x16x32_bf16(af[mi], bfr[ni], acc[mi][ni], 0, 0, 0);
        __syncthreads();
      }

      #pragma unroll
      for (int ni = 0; ni < 4; ++ni) {
        const int colc = tn * 128 + wn * 64 + ni * 16 + l15;
        const float bv = bias[colc];
        #pragma unroll
        for (int mi = 0; mi < 4; ++mi) {
          const int row0 = tm * 128 + wm * 64 + mi * 16 + lhi * 4;
          #pragma unroll
          for (int q = 0; q < 4; ++q)
            Y[(size_t)(row0 + q) * VSZ + colc] = acc[mi][ni][q] + bv;
        }
      }
    }
  }
}

// ---------------- fallback out GEMM (narrow ws): f32 B with in-kernel conversion --------------
__global__ __launch_bounds__(256) void out_gemm_kernel(
    const unsigned short* __restrict__ A,
    const float* __restrict__ Bw,
    const float* __restrict__ bias,
    float* __restrict__ Y)
{
  __shared__ unsigned short As[128 * 32];
  __shared__ unsigned short Bs[128 * 32];
  const int bid = blockIdx.x;
  const int s  = (bid & 7) * 2000 + (bid >> 3);
  const int tn = s >> 6, tm = s & 63;
  const int tid = threadIdx.x;
  const int wave = tid >> 6, lane = tid & 63;
  const int wm = wave >> 1, wn = wave & 1;
  const int l15 = lane & 15, lhi = lane >> 4;
  f32x4 acc[4][4] = {};

  for (int k0 = 0; k0 < 512; k0 += 32) {
    #pragma unroll
    for (int it = 0; it < 2; ++it) {
      const int ss  = tid + it * 256;
      const int row = ss >> 2;
      const int c8  = (ss & 3) << 3;
      *(uint4*)(As + row * 32 + c8) =
          *(const uint4*)(A + (size_t)(tm * 128 + row) * 512 + k0 + c8);
      const float4 b0 = *(const float4*)(Bw + (size_t)(tn * 128 + row) * 512 + k0 + c8);
      const float4 b1 = *(const float4*)(Bw + (size_t)(tn * 128 + row) * 512 + k0 + c8 + 4);
      union { unsigned short h[8]; uint4 u; } cv;
      cv.h[0] = f2bf(b0.x); cv.h[1] = f2bf(b0.y); cv.h[2] = f2bf(b0.z); cv.h[3] = f2bf(b0.w);
      cv.h[4] = f2bf(b1.x); cv.h[5] = f2bf(b1.y); cv.h[6] = f2bf(b1.z); cv.h[7] = f2bf(b1.w);
      *(uint4*)(Bs + row * 32 + c8) = cv.u;
    }
    __syncthreads();
    sh8 af[4], bfr[4];
    #pragma unroll
    for (int mi = 0; mi < 4; ++mi)
      af[mi] = *(const sh8*)(As + (wm * 64 + mi * 16 + l15) * 32 + lhi * 8);
    #pragma unroll
    for (int ni = 0; ni < 4; ++ni)
      bfr[ni] = *(const sh8*)(Bs + (wn * 64 + ni * 16 + l15) * 32 + lhi * 8);
    #pragma unroll
    for (int mi = 0; mi < 4; ++mi)
      #pragma unroll
      for (int ni = 0; ni < 4; ++ni)
        acc[mi][ni] = __builtin_amdgcn_mfma_f32_16x16x32_bf16(af[mi], bfr[ni], acc[mi][ni], 0, 0, 0);
    __syncthreads();
  }

  #pragma unroll
  for (int ni = 0; ni < 4; ++ni) {
    const int col = tn * 128 + wn * 64 + ni * 16 + l15;
    const float bv = bias[col];
    #pragma unroll
    for (int mi = 0; mi < 4; ++mi) {
      const int row0 = tm * 128 + wm * 64 + mi * 16 + lhi * 4;
      #pragma unroll
      for (int q = 0; q < 4; ++q)
        Y[(size_t)(row0 + q) * VSZ + col] = acc[mi][ni][q] + bv;
    }
  }
}

extern "C" void kernel_launch(void* const* d_in, const int* in_sizes, int n_in,
                              void* d_out, int out_size, void* d_ws, size_t ws_size,
                              hipStream_t stream)
{
  const int*   x   = (const int*)  d_in[0];
  const float* emb = (const float*)d_in[1];
  const float* Wr  = (const float*)d_in[2];
  const float* Br  = (const float*)d_in[3];
  const float* Wz  = (const float*)d_in[4];
  const float* Bz  = (const float*)d_in[5];
  const float* Wh  = (const float*)d_in[6];
  const float* Bh  = (const float*)d_in[7];
  const float* W   = (const float*)d_in[8];
  const float* bo  = (const float*)d_in[9];
  float* out = (float*)d_out;

  char* ws = (char*)d_ws;
  _Float16*       hF     = (_Float16*)(ws);                 //  64 KiB [64][512]
  _Float16*       uF     = (_Float16*)(ws + 65536);         //  64 KiB [64][512]
  unsigned*       flagsA = (unsigned*)(ws + 131072);        //  16 KiB (128 slots x 128B)
  unsigned*       flagsB = (unsigned*)(ws + 147456);        //  16 KiB
  unsigned short* Habf   = (unsigned short*)(ws + 163840);  //   8 MiB bf16 h history
  unsigned short* Wbf    = (unsigned short*)(ws + 163840 + 8388608);  // 32.7 MiB bf16 W
  const bool wide = ws_size >= (size_t)(163840 + 8388608 + (size_t)VSZ * HD * 2);

  // XG (pre-projection) overlays d_out rows < 394; consumer tiles for those rows run last.
  float* XG   = out;                  // [8192][1536]
  float* outT = out + 262144000ll;    // hT.T region

  (void)hipMemsetAsync(ws, 0, 163840, stream);

  proj_kernel<<<dim3(12, 64), 256, 0, stream>>>(x, emb, Wr, Br, Wz, Bz, Wh, Bh, XG);
  if (wide) {
    wconv_kernel<<<8000, 256, 0, stream>>>(W, Wbf);
    fused_kernel<<<NWG + NGW, 256, 0, stream>>>(XG, Wr, Wz, Wh, hF, uF, Habf, outT,
                                                flagsA, flagsB, Wbf, bo, out);
  } else {
    fused_kernel<<<NWG, 256, 0, stream>>>(XG, Wr, Wz, Wh, hF, uF, Habf, outT,
                                          flagsA, flagsB, (const unsigned short*)nullptr,
                                          bo, out);
    out_gemm_kernel<<<16000, 256, 0, stream>>>(Habf, W, bo, out);
  }
}